// Round 6
// baseline (665.509 us; speedup 1.0000x reference)
//
#include <hip/hip_runtime.h>

#define N_NODES  100000
#define N_EDGES  2000000
#define N_GRAPHS 1000
#define NFEAT    7
#define BN_EPS   1e-5f
#define MAXDEG   64   // in-degree ~ Poisson(20); P(max over 100k > 63) < 1e-9

// bf16 helpers (storage only; all arithmetic fp32)
__device__ __forceinline__ unsigned bf16_rne(float f) {
  unsigned u = __float_as_uint(f);
  return (u + 0x7FFFu + ((u >> 16) & 1u)) >> 16;
}
__device__ __forceinline__ float bf16_lo(unsigned u) { return __uint_as_float(u << 16); }
__device__ __forceinline__ float bf16_hi(unsigned u) { return __uint_as_float(u & 0xFFFF0000u); }

// ---------------- padded single-pass CSR build (proven) ----------------
__global__ void build_csr_kernel(const int* __restrict__ src, const int* __restrict__ dst,
                                 int* __restrict__ cnt, int* __restrict__ csr) {
  int e = blockIdx.x * 256 + threadIdx.x;
  if (e < N_EDGES) {
    int d = dst[e];
    int slot = atomicAdd(&cnt[d], 1);
    if (slot < MAXDEG) csr[d * MAXDEG + slot] = src[e];
  }
}

// ---------------- conv1: DIN=7 fp32 scalar gather -> bf16 out ----------------
__global__ __launch_bounds__(256) void gin_layer7(
    const float* __restrict__ hin, const int* __restrict__ cnt,
    const int* __restrict__ csr,
    const float* __restrict__ W1, const float* __restrict__ b1,
    const float* __restrict__ W2, const float* __restrict__ b2,
    const float* __restrict__ gamma, const float* __restrict__ beta,
    const float* __restrict__ mean, const float* __restrict__ var,
    unsigned short* __restrict__ hout16) {
  const int DIN = NFEAT;
  __shared__ float sW1[DIN * 32];
  __shared__ float sW2[1024];
  __shared__ float sb1[32], sb2[32], ssc[32], ssh[32];
  __shared__ float zb[4][33], tb[4][33];
  int tid = threadIdx.x;
  for (int i = tid; i < DIN * 32; i += 256) sW1[i] = W1[i];
  for (int i = tid; i < 1024; i += 256) sW2[i] = W2[i];
  if (tid < 32) {
    sb1[tid] = b1[tid];
    sb2[tid] = b2[tid];
    float sc = gamma[tid] * rsqrtf(var[tid] + BN_EPS);
    ssc[tid] = sc;
    ssh[tid] = beta[tid] - mean[tid] * sc;
  }
  __syncthreads();

  int w = tid >> 6, lane = tid & 63, half = lane >> 5, j = lane & 31;
  int node = blockIdx.x * 4 + w;

  int deg = cnt[node];
  if (deg > MAXDEG) deg = MAXDEG;
  const int* idx = csr + node * MAXDEG;
  int n0 = (deg + 1) >> 1;
  int beg = half ? n0 : 0;
  int end = half ? deg : n0;

  float a0 = 0.f, a1 = 0.f, a2 = 0.f, a3 = 0.f;
  int t = beg;
  for (; t + 3 < end; t += 4) {
    int s0 = idx[t], s1 = idx[t + 1], s2 = idx[t + 2], s3 = idx[t + 3];
    if (j < DIN) {
      a0 += hin[s0 * DIN + j];
      a1 += hin[s1 * DIN + j];
      a2 += hin[s2 * DIN + j];
      a3 += hin[s3 * DIN + j];
    }
  }
  for (; t < end; ++t) {
    int s = idx[t];
    if (j < DIN) a0 += hin[s * DIN + j];
  }
  float acc = (a0 + a1) + (a2 + a3);
  acc += __shfl_xor(acc, 32);
  if (j < DIN) acc += hin[node * DIN + j];  // (1+eps)*x, eps=0
  if (half == 0) zb[w][j] = acc;            // same-wave LDS

  constexpr int KM = DIN / 2;
  float tp = half ? 0.f : sb1[j];
  {
    int k0 = half ? KM : 0, k1 = half ? DIN : KM;
    for (int k = k0; k < k1; ++k) tp = fmaf(zb[w][k], sW1[k * 32 + j], tp);
  }
  tp += __shfl_xor(tp, 32);
  tp = fmaxf(tp, 0.f);
  if (half == 0) tb[w][j] = tp;

  float op = half ? 0.f : sb2[j];
  {
    int k0 = half ? 16 : 0, k1 = half ? 32 : 16;
    for (int k = k0; k < k1; ++k) op = fmaf(tb[w][k], sW2[k * 32 + j], op);
  }
  op += __shfl_xor(op, 32);
  if (half == 0) {
    op = fmaxf(op, 0.f);
    op = op * ssc[j] + ssh[j];
    float hi = __shfl(op, j | 1);       // odd-lane partner (within half 0)
    if ((j & 1) == 0) {
      unsigned pk = bf16_rne(op) | (bf16_rne(hi) << 16);
      ((unsigned*)hout16)[node * 16 + (j >> 1)] = pk;
    }
  }
}

// ---------------- conv2..5: bf16 row gather (1 line/row) -> bf16 out ----------------
// One wave per node. Lane l: edge group grp=l>>2 (16 groups), chunk ch=l&3
// (uint4 = 8 bf16 dims). 4 predicated steps cover deg+self <= 64 with up to
// 16 rows in flight per step. All arithmetic fp32.
__global__ __launch_bounds__(256) void gin_layer32(
    const unsigned short* __restrict__ hin16, const int* __restrict__ cnt,
    const int* __restrict__ csr,
    const float* __restrict__ W1, const float* __restrict__ b1,
    const float* __restrict__ W2, const float* __restrict__ b2,
    const float* __restrict__ gamma, const float* __restrict__ beta,
    const float* __restrict__ mean, const float* __restrict__ var,
    unsigned short* __restrict__ hout16) {
  __shared__ float sW1[1024];
  __shared__ float sW2[1024];
  __shared__ float sb1[32], sb2[32], ssc[32], ssh[32];
  __shared__ float zb[4][33], tb[4][33];
  int tid = threadIdx.x;
  for (int i = tid; i < 1024; i += 256) { sW1[i] = W1[i]; sW2[i] = W2[i]; }
  if (tid < 32) {
    sb1[tid] = b1[tid];
    sb2[tid] = b2[tid];
    float sc = gamma[tid] * rsqrtf(var[tid] + BN_EPS);
    ssc[tid] = sc;
    ssh[tid] = beta[tid] - mean[tid] * sc;
  }
  __syncthreads();  // only block barrier

  int w = tid >> 6, lane = tid & 63;
  int node = blockIdx.x * 4 + w;

  int deg = cnt[node];
  if (deg > 63) deg = 63;
  int degE = deg + 1;                                         // + self
  int idxv = (lane < deg) ? csr[node * MAXDEG + lane] : node; // one coalesced load
  int grp = lane >> 2;
  int ch  = lane & 3;
  const uint4* h4 = (const uint4*)hin16;  // 4 × uint4 per 64 B row

  float a[8] = {0.f, 0.f, 0.f, 0.f, 0.f, 0.f, 0.f, 0.f};
#pragma unroll
  for (int s = 0; s < 4; ++s) {
    int e = s * 16 + grp;
    int sid = __shfl(idxv, e);
    if (e < degE) {
      uint4 v = h4[(size_t)sid * 4 + ch];
      a[0] += bf16_lo(v.x); a[1] += bf16_hi(v.x);
      a[2] += bf16_lo(v.y); a[3] += bf16_hi(v.y);
      a[4] += bf16_lo(v.z); a[5] += bf16_hi(v.z);
      a[6] += bf16_lo(v.w); a[7] += bf16_hi(v.w);
    }
  }
#pragma unroll
  for (int mask = 4; mask <= 32; mask <<= 1) {
#pragma unroll
    for (int q = 0; q < 8; ++q) a[q] += __shfl_xor(a[q], mask);
  }
  if (lane < 4) {  // lane == ch: full sums for dims [ch*8, ch*8+8)
#pragma unroll
    for (int q = 0; q < 8; ++q) zb[w][lane * 8 + q] = a[q];
  }

  // MLP split-k across halves (proven pattern)
  int half = lane >> 5, j = lane & 31;
  float tp = half ? 0.f : sb1[j];
  {
    int k0 = half ? 16 : 0, k1 = half ? 32 : 16;
    for (int k = k0; k < k1; ++k) tp = fmaf(zb[w][k], sW1[k * 32 + j], tp);
  }
  tp += __shfl_xor(tp, 32);
  tp = fmaxf(tp, 0.f);
  if (half == 0) tb[w][j] = tp;

  float op = half ? 0.f : sb2[j];
  {
    int k0 = half ? 16 : 0, k1 = half ? 32 : 16;
    for (int k = k0; k < k1; ++k) op = fmaf(tb[w][k], sW2[k * 32 + j], op);
  }
  op += __shfl_xor(op, 32);
  if (half == 0) {
    op = fmaxf(op, 0.f);
    op = op * ssc[j] + ssh[j];
    float hi = __shfl(op, j | 1);
    if ((j & 1) == 0) {
      unsigned pk = bf16_rne(op) | (bf16_rne(hi) << 16);
      ((unsigned*)hout16)[node * 16 + (j >> 1)] = pk;
    }
  }
}

// ---------------- pool: one block per graph (batch sorted), bf16 in ----------------
__global__ __launch_bounds__(256) void pool_kernel(const unsigned short* __restrict__ h16,
                                                   const int* __restrict__ batch,
                                                   float* __restrict__ g) {
  __shared__ int s_lo, s_hi;
  __shared__ float red[8][33];
  int gr = blockIdx.x;
  if (threadIdx.x == 0) {
    int lo = 0, hi = N_NODES;
    while (lo < hi) { int m = (lo + hi) >> 1; if (batch[m] < gr) lo = m + 1; else hi = m; }
    s_lo = lo;
  } else if (threadIdx.x == 1) {
    int lo = 0, hi = N_NODES;
    while (lo < hi) { int m = (lo + hi) >> 1; if (batch[m] < gr + 1) lo = m + 1; else hi = m; }
    s_hi = lo;
  }
  __syncthreads();
  int lo = s_lo, hi = s_hi;
  int j = threadIdx.x & 31;
  int nd = threadIdx.x >> 5;
  float acc = 0.f;
  for (int n = lo + nd; n < hi; n += 8)
    acc += __uint_as_float((unsigned)h16[n * 32 + j] << 16);
  red[nd][j] = acc;
  __syncthreads();
  if (threadIdx.x < 32) {
    float s = 0.f;
#pragma unroll
    for (int r = 0; r < 8; ++r) s += red[r][j];
    g[gr * 32 + j] = s;
  }
}

// ---------------- head (fp32) ----------------
__global__ __launch_bounds__(256) void head_kernel(
    const float* __restrict__ g, const float* __restrict__ W1, const float* __restrict__ b1,
    const float* __restrict__ W2, const float* __restrict__ b2, float* __restrict__ out) {
  __shared__ float sW1[1024], sb1[32];
  __shared__ float sW2[64], sb2[2];
  __shared__ float zb[8][33], tb[8][33], lb[8][2];
  int tid = threadIdx.x;
  for (int i = tid; i < 1024; i += 256) sW1[i] = W1[i];
  if (tid < 64) sW2[tid] = W2[tid];
  if (tid < 32) sb1[tid] = b1[tid];
  if (tid < 2) sb2[tid] = b2[tid];
  int nd = tid >> 5;
  int gr = blockIdx.x * 8 + nd;
  int j = tid & 31;
  __syncthreads();
  float z = (gr < N_GRAPHS) ? g[gr * 32 + j] : 0.f;
  zb[nd][j] = z;
  __syncthreads();
  float t = sb1[j];
#pragma unroll
  for (int k = 0; k < 32; ++k) t = fmaf(zb[nd][k], sW1[k * 32 + j], t);
  t = fmaxf(t, 0.f);
  tb[nd][j] = t;
  __syncthreads();
  if (j < 2) {
    float l = sb2[j];
#pragma unroll
    for (int k = 0; k < 32; ++k) l = fmaf(tb[nd][k], sW2[k * 2 + j], l);
    lb[nd][j] = l;
  }
  __syncthreads();
  if (gr < N_GRAPHS && j < 2) {
    float l0 = lb[nd][0], l1 = lb[nd][1];
    float m = fmaxf(l0, l1);
    float lse = m + logf(expf(l0 - m) + expf(l1 - m));
    out[gr * 2 + j] = lb[nd][j] - lse;
  }
}

extern "C" void kernel_launch(void* const* d_in, const int* in_sizes, int n_in,
                              void* d_out, int out_size, void* d_ws, size_t ws_size,
                              hipStream_t stream) {
  const float* x     = (const float*)d_in[0];
  const int*   eidx  = (const int*)d_in[1];
  const int*   batch = (const int*)d_in[2];
  const float* c1W1  = (const float*)d_in[3];
  const float* c1b1  = (const float*)d_in[4];
  const float* c1W2  = (const float*)d_in[5];
  const float* c1b2  = (const float*)d_in[6];
  const float* csW1  = (const float*)d_in[7];
  const float* csb1  = (const float*)d_in[8];
  const float* csW2  = (const float*)d_in[9];
  const float* csb2  = (const float*)d_in[10];
  const float* bng   = (const float*)d_in[11];
  const float* bnb   = (const float*)d_in[12];
  const float* bnm   = (const float*)d_in[13];
  const float* bnv   = (const float*)d_in[14];
  const float* fc1W  = (const float*)d_in[15];
  const float* fc1b  = (const float*)d_in[16];
  const float* fc2W  = (const float*)d_in[17];
  const float* fc2b  = (const float*)d_in[18];
  float* out = (float*)d_out;

  const int* src = eidx;
  const int* dst = eidx + N_EDGES;

  // workspace (~39.2 MB)
  char* p = (char*)d_ws;
  unsigned short* hA16 = (unsigned short*)p; p += (size_t)N_NODES * 32 * 2;  // 6.4 MB, 16B-aligned
  unsigned short* hB16 = (unsigned short*)p; p += (size_t)N_NODES * 32 * 2;  // 6.4 MB
  int*   cnt = (int*)p;   p += (size_t)N_NODES * 4;                          // 0.4 MB
  int*   csr = (int*)p;   p += (size_t)N_NODES * MAXDEG * 4;                 // 25.6 MB
  float* g   = (float*)p; p += (size_t)N_GRAPHS * 32 * 4;

  // ---- build padded CSR (proven) ----
  hipMemsetAsync(cnt, 0, (size_t)N_NODES * 4, stream);
  build_csr_kernel<<<(N_EDGES + 255) / 256, 256, 0, stream>>>(src, dst, cnt, csr);

  const int NBLK = N_NODES / 4;  // 4 nodes (waves) per block

  // ---- conv1 (7->32) + relu + bn0, bf16 out ----
  gin_layer7<<<NBLK, 256, 0, stream>>>(
      x, cnt, csr, c1W1, c1b1, c1W2, c1b2, bng, bnb, bnm, bnv, hA16);

  // ---- conv2..5 (32->32) + relu + bn1..4, bf16 gather ----
  unsigned short* cur = hA16;
  unsigned short* nxt = hB16;
  for (int i = 0; i < 4; ++i) {
    gin_layer32<<<NBLK, 256, 0, stream>>>(
        cur, cnt, csr,
        csW1 + (size_t)i * 1024, csb1 + (size_t)i * 32,
        csW2 + (size_t)i * 1024, csb2 + (size_t)i * 32,
        bng + (size_t)(i + 1) * 32, bnb + (size_t)(i + 1) * 32,
        bnm + (size_t)(i + 1) * 32, bnv + (size_t)(i + 1) * 32, nxt);
    unsigned short* tmp = cur; cur = nxt; nxt = tmp;
  }

  pool_kernel<<<N_GRAPHS, 256, 0, stream>>>(cur, batch, g);
  head_kernel<<<(N_GRAPHS + 7) / 8, 256, 0, stream>>>(g, fc1W, fc1b, fc2W, fc2b, out);
}

// Round 7
// 549.640 us; speedup vs baseline: 1.2108x; 1.2108x over previous
//
#include <hip/hip_runtime.h>

#define N_NODES  100000
#define N_EDGES  2000000
#define N_GRAPHS 1000
#define NFEAT    7
#define BN_EPS   1e-5f
#define MAXDEG   64    // in-degree ~ Poisson(20); P(max over 100k > 63) < 1e-9

#define BSH      7     // 128-node dst buckets
#define NBKT     782   // ceil(100000/128)
#define BCAP     3584  // per-bucket edge cap: mean 2560 + 20 sigma
#define E_PER_BLK 16384

// bf16 helpers (storage only; all arithmetic fp32)
__device__ __forceinline__ unsigned bf16_rne(float f) {
  unsigned u = __float_as_uint(f);
  return (u + 0x7FFFu + ((u >> 16) & 1u)) >> 16;
}
__device__ __forceinline__ float bf16_lo(unsigned u) { return __uint_as_float(u << 16); }
__device__ __forceinline__ float bf16_hi(unsigned u) { return __uint_as_float(u & 0xFFFF0000u); }

// ---------------- b1: bucket edges by dst>>7, block-contiguous writes ----------------
// packed entry: (d & 127) << 17 | src   (src < 2^17)
__global__ __launch_bounds__(1024) void b1_bucket(const int* __restrict__ src,
                                                  const int* __restrict__ dst,
                                                  int* __restrict__ gCur,
                                                  unsigned* __restrict__ ebuf) {
  __shared__ int hist[NBKT], base[NBKT];
  int tid = threadIdx.x;
  for (int i = tid; i < NBKT; i += 1024) hist[i] = 0;
  __syncthreads();
  unsigned pk[16];
  int bo[16];
  int e0 = blockIdx.x * E_PER_BLK;
#pragma unroll
  for (int k = 0; k < 16; ++k) {
    int e = e0 + k * 1024 + tid;
    if (e < N_EDGES) {
      int d = dst[e], s = src[e];
      int b = d >> BSH;
      int off = atomicAdd(&hist[b], 1);          // per-block slot
      pk[k] = ((unsigned)(d & 127) << 17) | (unsigned)s;
      bo[k] = (b << 17) | off;                   // b<782 (10b), off<16384 (14b)
    } else {
      bo[k] = -1;
    }
  }
  __syncthreads();
  for (int i = tid; i < NBKT; i += 1024)
    base[i] = hist[i] ? atomicAdd(&gCur[i], hist[i]) : 0;  // global reservation
  __syncthreads();
#pragma unroll
  for (int k = 0; k < 16; ++k) {
    if (bo[k] >= 0) {
      int b = bo[k] >> 17, off = bo[k] & 0x1FFFF;
      int p = base[b] + off;
      if (p < BCAP) ebuf[(size_t)b * BCAP + p] = pk[k];  // ~21 consecutive/bucket/block
    }
  }
}

// ---------------- b2: one block per bucket -> padded csr + cnt ----------------
// LDS slot-assign into the padded per-node layout, then fully sequential flush.
// csr layout is IDENTICAL to the proven consumers: csr[node*64 + slot].
__global__ __launch_bounds__(256) void b2_csr(const unsigned* __restrict__ ebuf,
                                              const int* __restrict__ gCnt,
                                              int* __restrict__ cnt,
                                              int* __restrict__ csr) {
  __shared__ int hist[128];
  __shared__ int stage[128 * MAXDEG];  // 32 KB; garbage in unused slots never read
  int b = blockIdx.x, tid = threadIdx.x;
  if (tid < 128) hist[tid] = 0;
  __syncthreads();
  int n = gCnt[b];
  if (n > BCAP) n = BCAP;
  const unsigned* eb = ebuf + (size_t)b * BCAP;
  for (int i = tid; i < n; i += 256) {
    unsigned pk = eb[i];
    int dloc = (int)(pk >> 17);
    int slot = atomicAdd(&hist[dloc], 1);
    if (slot < MAXDEG) stage[(dloc << 6) + slot] = (int)(pk & 0x1FFFFu);
  }
  __syncthreads();
  if (tid < 128) {
    int gnode = (b << BSH) + tid;
    if (gnode < N_NODES) cnt[gnode] = hist[tid];  // raw count; consumers cap
  }
  const int4* st4 = (const int4*)stage;
  int4* dst4 = (int4*)(csr + (size_t)b * (128 * MAXDEG));
  for (int i = tid; i < 128 * MAXDEG / 4; i += 256) dst4[i] = st4[i];  // sequential
}

// ---------------- conv1: DIN=7 fp32 scalar gather -> bf16 out (proven) ----------------
__global__ __launch_bounds__(256) void gin_layer7(
    const float* __restrict__ hin, const int* __restrict__ cnt,
    const int* __restrict__ csr,
    const float* __restrict__ W1, const float* __restrict__ b1,
    const float* __restrict__ W2, const float* __restrict__ b2,
    const float* __restrict__ gamma, const float* __restrict__ beta,
    const float* __restrict__ mean, const float* __restrict__ var,
    unsigned short* __restrict__ hout16) {
  const int DIN = NFEAT;
  __shared__ float sW1[DIN * 32];
  __shared__ float sW2[1024];
  __shared__ float sb1[32], sb2[32], ssc[32], ssh[32];
  __shared__ float zb[4][33], tb[4][33];
  int tid = threadIdx.x;
  for (int i = tid; i < DIN * 32; i += 256) sW1[i] = W1[i];
  for (int i = tid; i < 1024; i += 256) sW2[i] = W2[i];
  if (tid < 32) {
    sb1[tid] = b1[tid];
    sb2[tid] = b2[tid];
    float sc = gamma[tid] * rsqrtf(var[tid] + BN_EPS);
    ssc[tid] = sc;
    ssh[tid] = beta[tid] - mean[tid] * sc;
  }
  __syncthreads();

  int w = tid >> 6, lane = tid & 63, half = lane >> 5, j = lane & 31;
  int node = blockIdx.x * 4 + w;

  int deg = cnt[node];
  if (deg > MAXDEG) deg = MAXDEG;
  const int* idx = csr + node * MAXDEG;
  int n0 = (deg + 1) >> 1;
  int beg = half ? n0 : 0;
  int end = half ? deg : n0;

  float a0 = 0.f, a1 = 0.f, a2 = 0.f, a3 = 0.f;
  int t = beg;
  for (; t + 3 < end; t += 4) {
    int s0 = idx[t], s1 = idx[t + 1], s2 = idx[t + 2], s3 = idx[t + 3];
    if (j < DIN) {
      a0 += hin[s0 * DIN + j];
      a1 += hin[s1 * DIN + j];
      a2 += hin[s2 * DIN + j];
      a3 += hin[s3 * DIN + j];
    }
  }
  for (; t < end; ++t) {
    int s = idx[t];
    if (j < DIN) a0 += hin[s * DIN + j];
  }
  float acc = (a0 + a1) + (a2 + a3);
  acc += __shfl_xor(acc, 32);
  if (j < DIN) acc += hin[node * DIN + j];  // (1+eps)*x, eps=0
  if (half == 0) zb[w][j] = acc;            // same-wave LDS

  constexpr int KM = DIN / 2;
  float tp = half ? 0.f : sb1[j];
  {
    int k0 = half ? KM : 0, k1 = half ? DIN : KM;
    for (int k = k0; k < k1; ++k) tp = fmaf(zb[w][k], sW1[k * 32 + j], tp);
  }
  tp += __shfl_xor(tp, 32);
  tp = fmaxf(tp, 0.f);
  if (half == 0) tb[w][j] = tp;

  float op = half ? 0.f : sb2[j];
  {
    int k0 = half ? 16 : 0, k1 = half ? 32 : 16;
    for (int k = k0; k < k1; ++k) op = fmaf(tb[w][k], sW2[k * 32 + j], op);
  }
  op += __shfl_xor(op, 32);
  if (half == 0) {
    op = fmaxf(op, 0.f);
    op = op * ssc[j] + ssh[j];
    float hi = __shfl(op, j | 1);
    if ((j & 1) == 0) {
      unsigned pk = bf16_rne(op) | (bf16_rne(hi) << 16);
      ((unsigned*)hout16)[node * 16 + (j >> 1)] = pk;
    }
  }
}

// ---------------- conv2..5: bf16 row gather (proven in R6) ----------------
__global__ __launch_bounds__(256) void gin_layer32(
    const unsigned short* __restrict__ hin16, const int* __restrict__ cnt,
    const int* __restrict__ csr,
    const float* __restrict__ W1, const float* __restrict__ b1,
    const float* __restrict__ W2, const float* __restrict__ b2,
    const float* __restrict__ gamma, const float* __restrict__ beta,
    const float* __restrict__ mean, const float* __restrict__ var,
    unsigned short* __restrict__ hout16) {
  __shared__ float sW1[1024];
  __shared__ float sW2[1024];
  __shared__ float sb1[32], sb2[32], ssc[32], ssh[32];
  __shared__ float zb[4][33], tb[4][33];
  int tid = threadIdx.x;
  for (int i = tid; i < 1024; i += 256) { sW1[i] = W1[i]; sW2[i] = W2[i]; }
  if (tid < 32) {
    sb1[tid] = b1[tid];
    sb2[tid] = b2[tid];
    float sc = gamma[tid] * rsqrtf(var[tid] + BN_EPS);
    ssc[tid] = sc;
    ssh[tid] = beta[tid] - mean[tid] * sc;
  }
  __syncthreads();  // only block barrier

  int w = tid >> 6, lane = tid & 63;
  int node = blockIdx.x * 4 + w;

  int deg = cnt[node];
  if (deg > 63) deg = 63;
  int degE = deg + 1;                                         // + self
  int idxv = (lane < deg) ? csr[node * MAXDEG + lane] : node; // one coalesced load
  int grp = lane >> 2;
  int ch  = lane & 3;
  const uint4* h4 = (const uint4*)hin16;  // 4 × uint4 per 64 B row

  float a[8] = {0.f, 0.f, 0.f, 0.f, 0.f, 0.f, 0.f, 0.f};
#pragma unroll
  for (int s = 0; s < 4; ++s) {
    int e = s * 16 + grp;
    int sid = __shfl(idxv, e);
    if (e < degE) {
      uint4 v = h4[(size_t)sid * 4 + ch];
      a[0] += bf16_lo(v.x); a[1] += bf16_hi(v.x);
      a[2] += bf16_lo(v.y); a[3] += bf16_hi(v.y);
      a[4] += bf16_lo(v.z); a[5] += bf16_hi(v.z);
      a[6] += bf16_lo(v.w); a[7] += bf16_hi(v.w);
    }
  }
#pragma unroll
  for (int mask = 4; mask <= 32; mask <<= 1) {
#pragma unroll
    for (int q = 0; q < 8; ++q) a[q] += __shfl_xor(a[q], mask);
  }
  if (lane < 4) {
#pragma unroll
    for (int q = 0; q < 8; ++q) zb[w][lane * 8 + q] = a[q];
  }

  int half = lane >> 5, j = lane & 31;
  float tp = half ? 0.f : sb1[j];
  {
    int k0 = half ? 16 : 0, k1 = half ? 32 : 16;
    for (int k = k0; k < k1; ++k) tp = fmaf(zb[w][k], sW1[k * 32 + j], tp);
  }
  tp += __shfl_xor(tp, 32);
  tp = fmaxf(tp, 0.f);
  if (half == 0) tb[w][j] = tp;

  float op = half ? 0.f : sb2[j];
  {
    int k0 = half ? 16 : 0, k1 = half ? 32 : 16;
    for (int k = k0; k < k1; ++k) op = fmaf(tb[w][k], sW2[k * 32 + j], op);
  }
  op += __shfl_xor(op, 32);
  if (half == 0) {
    op = fmaxf(op, 0.f);
    op = op * ssc[j] + ssh[j];
    float hi = __shfl(op, j | 1);
    if ((j & 1) == 0) {
      unsigned pk = bf16_rne(op) | (bf16_rne(hi) << 16);
      ((unsigned*)hout16)[node * 16 + (j >> 1)] = pk;
    }
  }
}

// ---------------- pool: one block per graph (batch sorted), bf16 in ----------------
__global__ __launch_bounds__(256) void pool_kernel(const unsigned short* __restrict__ h16,
                                                   const int* __restrict__ batch,
                                                   float* __restrict__ g) {
  __shared__ int s_lo, s_hi;
  __shared__ float red[8][33];
  int gr = blockIdx.x;
  if (threadIdx.x == 0) {
    int lo = 0, hi = N_NODES;
    while (lo < hi) { int m = (lo + hi) >> 1; if (batch[m] < gr) lo = m + 1; else hi = m; }
    s_lo = lo;
  } else if (threadIdx.x == 1) {
    int lo = 0, hi = N_NODES;
    while (lo < hi) { int m = (lo + hi) >> 1; if (batch[m] < gr + 1) lo = m + 1; else hi = m; }
    s_hi = lo;
  }
  __syncthreads();
  int lo = s_lo, hi = s_hi;
  int j = threadIdx.x & 31;
  int nd = threadIdx.x >> 5;
  float acc = 0.f;
  for (int n = lo + nd; n < hi; n += 8)
    acc += __uint_as_float((unsigned)h16[n * 32 + j] << 16);
  red[nd][j] = acc;
  __syncthreads();
  if (threadIdx.x < 32) {
    float s = 0.f;
#pragma unroll
    for (int r = 0; r < 8; ++r) s += red[r][j];
    g[gr * 32 + j] = s;
  }
}

// ---------------- head (fp32) ----------------
__global__ __launch_bounds__(256) void head_kernel(
    const float* __restrict__ g, const float* __restrict__ W1, const float* __restrict__ b1,
    const float* __restrict__ W2, const float* __restrict__ b2, float* __restrict__ out) {
  __shared__ float sW1[1024], sb1[32];
  __shared__ float sW2[64], sb2[2];
  __shared__ float zb[8][33], tb[8][33], lb[8][2];
  int tid = threadIdx.x;
  for (int i = tid; i < 1024; i += 256) sW1[i] = W1[i];
  if (tid < 64) sW2[tid] = W2[tid];
  if (tid < 32) sb1[tid] = b1[tid];
  if (tid < 2) sb2[tid] = b2[tid];
  int nd = tid >> 5;
  int gr = blockIdx.x * 8 + nd;
  int j = tid & 31;
  __syncthreads();
  float z = (gr < N_GRAPHS) ? g[gr * 32 + j] : 0.f;
  zb[nd][j] = z;
  __syncthreads();
  float t = sb1[j];
#pragma unroll
  for (int k = 0; k < 32; ++k) t = fmaf(zb[nd][k], sW1[k * 32 + j], t);
  t = fmaxf(t, 0.f);
  tb[nd][j] = t;
  __syncthreads();
  if (j < 2) {
    float l = sb2[j];
#pragma unroll
    for (int k = 0; k < 32; ++k) l = fmaf(tb[nd][k], sW2[k * 2 + j], l);
    lb[nd][j] = l;
  }
  __syncthreads();
  if (gr < N_GRAPHS && j < 2) {
    float l0 = lb[nd][0], l1 = lb[nd][1];
    float m = fmaxf(l0, l1);
    float lse = m + logf(expf(l0 - m) + expf(l1 - m));
    out[gr * 2 + j] = lb[nd][j] - lse;
  }
}

extern "C" void kernel_launch(void* const* d_in, const int* in_sizes, int n_in,
                              void* d_out, int out_size, void* d_ws, size_t ws_size,
                              hipStream_t stream) {
  const float* x     = (const float*)d_in[0];
  const int*   eidx  = (const int*)d_in[1];
  const int*   batch = (const int*)d_in[2];
  const float* c1W1  = (const float*)d_in[3];
  const float* c1b1  = (const float*)d_in[4];
  const float* c1W2  = (const float*)d_in[5];
  const float* c1b2  = (const float*)d_in[6];
  const float* csW1  = (const float*)d_in[7];
  const float* csb1  = (const float*)d_in[8];
  const float* csW2  = (const float*)d_in[9];
  const float* csb2  = (const float*)d_in[10];
  const float* bng   = (const float*)d_in[11];
  const float* bnb   = (const float*)d_in[12];
  const float* bnm   = (const float*)d_in[13];
  const float* bnv   = (const float*)d_in[14];
  const float* fc1W  = (const float*)d_in[15];
  const float* fc1b  = (const float*)d_in[16];
  const float* fc2W  = (const float*)d_in[17];
  const float* fc2b  = (const float*)d_in[18];
  float* out = (float*)d_out;

  const int* src = eidx;
  const int* dst = eidx + N_EDGES;

  // workspace (~50.6 MB; ws >= 51.8 MB proven by R2's padded path)
  char* p = (char*)d_ws;
  unsigned short* hA16 = (unsigned short*)p; p += (size_t)N_NODES * 32 * 2;   // 6.4 MB
  unsigned short* hB16 = (unsigned short*)p; p += (size_t)N_NODES * 32 * 2;   // 6.4 MB
  int*      cnt  = (int*)p;      p += (size_t)N_NODES * 4;                    // 0.4 MB
  int*      csr  = (int*)p;      p += (size_t)NBKT * 128 * MAXDEG * 4;        // 25.6 MB (bucket-padded)
  unsigned* ebuf = (unsigned*)p; p += (size_t)NBKT * BCAP * 4;                // 11.2 MB
  int*      gCur = (int*)p;      p += 1024 * 4;
  float*    g    = (float*)p;    p += (size_t)N_GRAPHS * 32 * 4;

  // ---- build: bucket pass + per-bucket padded-CSR pass ----
  hipMemsetAsync(gCur, 0, 1024 * 4, stream);
  b1_bucket<<<(N_EDGES + E_PER_BLK - 1) / E_PER_BLK, 1024, 0, stream>>>(src, dst, gCur, ebuf);
  b2_csr<<<NBKT, 256, 0, stream>>>(ebuf, gCur, cnt, csr);

  const int NBLK = N_NODES / 4;  // 4 nodes (waves) per block

  // ---- conv1 (7->32) + relu + bn0, bf16 out ----
  gin_layer7<<<NBLK, 256, 0, stream>>>(
      x, cnt, csr, c1W1, c1b1, c1W2, c1b2, bng, bnb, bnm, bnv, hA16);

  // ---- conv2..5 (32->32) + relu + bn1..4, bf16 gather ----
  unsigned short* cur = hA16;
  unsigned short* nxt = hB16;
  for (int i = 0; i < 4; ++i) {
    gin_layer32<<<NBLK, 256, 0, stream>>>(
        cur, cnt, csr,
        csW1 + (size_t)i * 1024, csb1 + (size_t)i * 32,
        csW2 + (size_t)i * 1024, csb2 + (size_t)i * 32,
        bng + (size_t)(i + 1) * 32, bnb + (size_t)(i + 1) * 32,
        bnm + (size_t)(i + 1) * 32, bnv + (size_t)(i + 1) * 32, nxt);
    unsigned short* tmp = cur; cur = nxt; nxt = tmp;
  }

  pool_kernel<<<N_GRAPHS, 256, 0, stream>>>(cur, batch, g);
  head_kernel<<<(N_GRAPHS + 7) / 8, 256, 0, stream>>>(g, fc1W, fc1b, fc2W, fc2b, out);
}

// Round 8
// 510.724 us; speedup vs baseline: 1.3031x; 1.0762x over previous
//
#include <hip/hip_runtime.h>

#define N_NODES  100000
#define N_EDGES  2000000
#define N_GRAPHS 1000
#define NFEAT    7
#define BN_EPS   1e-5f
#define MAXDEG   64    // in-degree ~ Poisson(20); P(max over 100k > 63) < 1e-9

#define BSH      7     // 128-node dst buckets
#define NBKT     782   // ceil(100000/128)
#define BCAP     3584  // per-bucket edge cap: mean 2560 + 20 sigma
#define E_PER_BLK 16384

// bf16 helpers (storage only; all arithmetic fp32)
__device__ __forceinline__ unsigned bf16_rne(float f) {
  unsigned u = __float_as_uint(f);
  return (u + 0x7FFFu + ((u >> 16) & 1u)) >> 16;
}
__device__ __forceinline__ float bf16_lo(unsigned u) { return __uint_as_float(u << 16); }
__device__ __forceinline__ float bf16_hi(unsigned u) { return __uint_as_float(u & 0xFFFF0000u); }

// ---------------- b1: bucket edges by dst>>7, block-contiguous writes (proven R7) ----------------
__global__ __launch_bounds__(1024) void b1_bucket(const int* __restrict__ src,
                                                  const int* __restrict__ dst,
                                                  int* __restrict__ gCur,
                                                  unsigned* __restrict__ ebuf) {
  __shared__ int hist[NBKT], base[NBKT];
  int tid = threadIdx.x;
  for (int i = tid; i < NBKT; i += 1024) hist[i] = 0;
  __syncthreads();
  unsigned pk[16];
  int bo[16];
  int e0 = blockIdx.x * E_PER_BLK;
#pragma unroll
  for (int k = 0; k < 16; ++k) {
    int e = e0 + k * 1024 + tid;
    if (e < N_EDGES) {
      int d = dst[e], s = src[e];
      int b = d >> BSH;
      int off = atomicAdd(&hist[b], 1);
      pk[k] = ((unsigned)(d & 127) << 17) | (unsigned)s;
      bo[k] = (b << 17) | off;
    } else {
      bo[k] = -1;
    }
  }
  __syncthreads();
  for (int i = tid; i < NBKT; i += 1024)
    base[i] = hist[i] ? atomicAdd(&gCur[i], hist[i]) : 0;
  __syncthreads();
#pragma unroll
  for (int k = 0; k < 16; ++k) {
    if (bo[k] >= 0) {
      int b = bo[k] >> 17, off = bo[k] & 0x1FFFF;
      int p = base[b] + off;
      if (p < BCAP) ebuf[(size_t)b * BCAP + p] = pk[k];
    }
  }
}

// ---------------- b2: one block per bucket -> padded csr + cnt (proven R7) ----------------
__global__ __launch_bounds__(256) void b2_csr(const unsigned* __restrict__ ebuf,
                                              const int* __restrict__ gCnt,
                                              int* __restrict__ cnt,
                                              int* __restrict__ csr) {
  __shared__ int hist[128];
  __shared__ int stage[128 * MAXDEG];
  int b = blockIdx.x, tid = threadIdx.x;
  if (tid < 128) hist[tid] = 0;
  __syncthreads();
  int n = gCnt[b];
  if (n > BCAP) n = BCAP;
  const unsigned* eb = ebuf + (size_t)b * BCAP;
  for (int i = tid; i < n; i += 256) {
    unsigned pk = eb[i];
    int dloc = (int)(pk >> 17);
    int slot = atomicAdd(&hist[dloc], 1);
    if (slot < MAXDEG) stage[(dloc << 6) + slot] = (int)(pk & 0x1FFFFu);
  }
  __syncthreads();
  if (tid < 128) {
    int gnode = (b << BSH) + tid;
    if (gnode < N_NODES) cnt[gnode] = hist[tid];
  }
  const int4* st4 = (const int4*)stage;
  int4* dst4 = (int4*)(csr + (size_t)b * (128 * MAXDEG));
  for (int i = tid; i < 128 * MAXDEG / 4; i += 256) dst4[i] = st4[i];
}

// ---------------- conv1: DIN=7 fp32 scalar gather -> bf16 out (proven) ----------------
__global__ __launch_bounds__(256) void gin_layer7(
    const float* __restrict__ hin, const int* __restrict__ cnt,
    const int* __restrict__ csr,
    const float* __restrict__ W1, const float* __restrict__ b1,
    const float* __restrict__ W2, const float* __restrict__ b2,
    const float* __restrict__ gamma, const float* __restrict__ beta,
    const float* __restrict__ mean, const float* __restrict__ var,
    unsigned short* __restrict__ hout16) {
  const int DIN = NFEAT;
  __shared__ float sW1[DIN * 32];
  __shared__ float sW2[1024];
  __shared__ float sb1[32], sb2[32], ssc[32], ssh[32];
  __shared__ float zb[4][33], tb[4][33];
  int tid = threadIdx.x;
  for (int i = tid; i < DIN * 32; i += 256) sW1[i] = W1[i];
  for (int i = tid; i < 1024; i += 256) sW2[i] = W2[i];
  if (tid < 32) {
    sb1[tid] = b1[tid];
    sb2[tid] = b2[tid];
    float sc = gamma[tid] * rsqrtf(var[tid] + BN_EPS);
    ssc[tid] = sc;
    ssh[tid] = beta[tid] - mean[tid] * sc;
  }
  __syncthreads();

  int w = tid >> 6, lane = tid & 63, half = lane >> 5, j = lane & 31;
  int node = blockIdx.x * 4 + w;

  int deg = cnt[node];
  if (deg > MAXDEG) deg = MAXDEG;
  const int* idx = csr + node * MAXDEG;
  int n0 = (deg + 1) >> 1;
  int beg = half ? n0 : 0;
  int end = half ? deg : n0;

  float a0 = 0.f, a1 = 0.f, a2 = 0.f, a3 = 0.f;
  int t = beg;
  for (; t + 3 < end; t += 4) {
    int s0 = idx[t], s1 = idx[t + 1], s2 = idx[t + 2], s3 = idx[t + 3];
    if (j < DIN) {
      a0 += hin[s0 * DIN + j];
      a1 += hin[s1 * DIN + j];
      a2 += hin[s2 * DIN + j];
      a3 += hin[s3 * DIN + j];
    }
  }
  for (; t < end; ++t) {
    int s = idx[t];
    if (j < DIN) a0 += hin[s * DIN + j];
  }
  float acc = (a0 + a1) + (a2 + a3);
  acc += __shfl_xor(acc, 32);
  if (j < DIN) acc += hin[node * DIN + j];  // (1+eps)*x, eps=0
  if (half == 0) zb[w][j] = acc;

  constexpr int KM = DIN / 2;
  float tp = half ? 0.f : sb1[j];
  {
    int k0 = half ? KM : 0, k1 = half ? DIN : KM;
    for (int k = k0; k < k1; ++k) tp = fmaf(zb[w][k], sW1[k * 32 + j], tp);
  }
  tp += __shfl_xor(tp, 32);
  tp = fmaxf(tp, 0.f);
  if (half == 0) tb[w][j] = tp;

  float op = half ? 0.f : sb2[j];
  {
    int k0 = half ? 16 : 0, k1 = half ? 32 : 16;
    for (int k = k0; k < k1; ++k) op = fmaf(tb[w][k], sW2[k * 32 + j], op);
  }
  op += __shfl_xor(op, 32);
  if (half == 0) {
    op = fmaxf(op, 0.f);
    op = op * ssc[j] + ssh[j];
    float hi = __shfl(op, j | 1);
    if ((j & 1) == 0) {
      unsigned pk = bf16_rne(op) | (bf16_rne(hi) << 16);
      ((unsigned*)hout16)[node * 16 + (j >> 1)] = pk;
    }
  }
}

// ---------------- conv2..5: instruction-lean persistent-wave layer ----------------
// One wave per node (looped). Lane = (edge parity = lane>>5, dim j = lane&31).
// Indices fetched on the SCALAR pipe (wave-uniform csr list -> s_load), rows
// loaded as coalesced 64 B ushort loads, reduction = single shfl_xor(32).
// MLP: weights in VGPRs (split-k by half), z/t broadcast via tiny LDS.
__global__ __launch_bounds__(256) void gin_layer32(
    const unsigned short* __restrict__ hin16, const int* __restrict__ cnt,
    const int* __restrict__ csr,
    const float* __restrict__ W1, const float* __restrict__ b1,
    const float* __restrict__ W2, const float* __restrict__ b2,
    const float* __restrict__ gamma, const float* __restrict__ beta,
    const float* __restrict__ mean, const float* __restrict__ var,
    unsigned short* __restrict__ hout16) {
  __shared__ __align__(16) float zs[4][32];
  __shared__ __align__(16) float ts[4][32];
  int tid = threadIdx.x;
  int w = __builtin_amdgcn_readfirstlane(tid >> 6);  // wave id, force-scalar
  int lane = tid & 63;
  int half = lane >> 5, j = lane & 31;

  // per-thread weight columns: my half's k-range (coalesced loads, L2-hot)
  float wr1[16], wr2[16];
#pragma unroll
  for (int i = 0; i < 16; ++i) wr1[i] = W1[(half * 16 + i) * 32 + j];
#pragma unroll
  for (int i = 0; i < 16; ++i) wr2[i] = W2[(half * 16 + i) * 32 + j];
  float vb1 = b1[j], vb2 = b2[j];
  float sc = gamma[j] * rsqrtf(var[j] + BN_EPS);
  float sh = beta[j] - mean[j] * sc;

  const int NW = gridDim.x * 4;  // total waves
  for (int node = blockIdx.x * 4 + w; node < N_NODES; node += NW) {
    int deg = cnt[node];  // uniform -> scalar load
    if (deg > 63) deg = 63;
    const int* ip = csr + node * MAXDEG;  // uniform base

    float a0 = 0.f, a1 = 0.f, a2 = 0.f, a3 = 0.f;
    if (!half) {  // self term (1+eps)*x, eps=0
      unsigned hv = hin16[node * 32 + j];
      a0 = __uint_as_float(hv << 16);
    }
    int t = 0;
    for (; t + 8 <= deg; t += 8) {  // 8 edges, no predication; indices via s_load
      int sA = half ? ip[t + 1] : ip[t + 0];
      int sB = half ? ip[t + 3] : ip[t + 2];
      int sC = half ? ip[t + 5] : ip[t + 4];
      int sD = half ? ip[t + 7] : ip[t + 6];
      unsigned hA = hin16[(size_t)sA * 32 + j];
      unsigned hB = hin16[(size_t)sB * 32 + j];
      unsigned hC = hin16[(size_t)sC * 32 + j];
      unsigned hD = hin16[(size_t)sD * 32 + j];
      a0 += __uint_as_float(hA << 16);
      a1 += __uint_as_float(hB << 16);
      a2 += __uint_as_float(hC << 16);
      a3 += __uint_as_float(hD << 16);
    }
    for (; t < deg; t += 2) {  // tail pairs; loads predicated by e<deg
      int s0 = ip[t];
      int s1 = ip[t + 1];  // in-bounds (t+1 <= 63); value unused if masked
      int s = half ? s1 : s0;
      if (t + half < deg) {
        unsigned hv = hin16[(size_t)s * 32 + j];
        a0 += __uint_as_float(hv << 16);
      }
    }
    float z = (a0 + a1) + (a2 + a3);
    z += __shfl_xor(z, 32);          // combine even/odd-edge halves
    if (!half) zs[w][j] = z;         // same-wave LDS, in-order pipe

    // GEMM1: relu(z @ W1 + b1), split-k across halves, weights in VGPRs
    float tp = half ? 0.f : vb1;
    {
      const float4* zp = (const float4*)&zs[w][half * 16];
      float4 z0 = zp[0], z1 = zp[1], z2 = zp[2], z3 = zp[3];
      tp = fmaf(z0.x, wr1[0], tp);  tp = fmaf(z0.y, wr1[1], tp);
      tp = fmaf(z0.z, wr1[2], tp);  tp = fmaf(z0.w, wr1[3], tp);
      tp = fmaf(z1.x, wr1[4], tp);  tp = fmaf(z1.y, wr1[5], tp);
      tp = fmaf(z1.z, wr1[6], tp);  tp = fmaf(z1.w, wr1[7], tp);
      tp = fmaf(z2.x, wr1[8], tp);  tp = fmaf(z2.y, wr1[9], tp);
      tp = fmaf(z2.z, wr1[10], tp); tp = fmaf(z2.w, wr1[11], tp);
      tp = fmaf(z3.x, wr1[12], tp); tp = fmaf(z3.y, wr1[13], tp);
      tp = fmaf(z3.z, wr1[14], tp); tp = fmaf(z3.w, wr1[15], tp);
    }
    tp += __shfl_xor(tp, 32);
    tp = fmaxf(tp, 0.f);
    if (!half) ts[w][j] = tp;

    // GEMM2 + relu + BN(eval)
    float op = half ? 0.f : vb2;
    {
      const float4* tpp = (const float4*)&ts[w][half * 16];
      float4 t0 = tpp[0], t1 = tpp[1], t2 = tpp[2], t3 = tpp[3];
      op = fmaf(t0.x, wr2[0], op);  op = fmaf(t0.y, wr2[1], op);
      op = fmaf(t0.z, wr2[2], op);  op = fmaf(t0.w, wr2[3], op);
      op = fmaf(t1.x, wr2[4], op);  op = fmaf(t1.y, wr2[5], op);
      op = fmaf(t1.z, wr2[6], op);  op = fmaf(t1.w, wr2[7], op);
      op = fmaf(t2.x, wr2[8], op);  op = fmaf(t2.y, wr2[9], op);
      op = fmaf(t2.z, wr2[10], op); op = fmaf(t2.w, wr2[11], op);
      op = fmaf(t3.x, wr2[12], op); op = fmaf(t3.y, wr2[13], op);
      op = fmaf(t3.z, wr2[14], op); op = fmaf(t3.w, wr2[15], op);
    }
    op += __shfl_xor(op, 32);
    if (!half) {
      op = fmaxf(op, 0.f) * sc + sh;
      float hi = __shfl(op, j | 1);
      if ((j & 1) == 0) {
        unsigned pk = bf16_rne(op) | (bf16_rne(hi) << 16);
        ((unsigned*)hout16)[node * 16 + (j >> 1)] = pk;
      }
    }
  }
}

// ---------------- pool: one block per graph (batch sorted), bf16 in ----------------
__global__ __launch_bounds__(256) void pool_kernel(const unsigned short* __restrict__ h16,
                                                   const int* __restrict__ batch,
                                                   float* __restrict__ g) {
  __shared__ int s_lo, s_hi;
  __shared__ float red[8][33];
  int gr = blockIdx.x;
  if (threadIdx.x == 0) {
    int lo = 0, hi = N_NODES;
    while (lo < hi) { int m = (lo + hi) >> 1; if (batch[m] < gr) lo = m + 1; else hi = m; }
    s_lo = lo;
  } else if (threadIdx.x == 1) {
    int lo = 0, hi = N_NODES;
    while (lo < hi) { int m = (lo + hi) >> 1; if (batch[m] < gr + 1) lo = m + 1; else hi = m; }
    s_hi = lo;
  }
  __syncthreads();
  int lo = s_lo, hi = s_hi;
  int j = threadIdx.x & 31;
  int nd = threadIdx.x >> 5;
  float acc = 0.f;
  for (int n = lo + nd; n < hi; n += 8)
    acc += __uint_as_float((unsigned)h16[n * 32 + j] << 16);
  red[nd][j] = acc;
  __syncthreads();
  if (threadIdx.x < 32) {
    float s = 0.f;
#pragma unroll
    for (int r = 0; r < 8; ++r) s += red[r][j];
    g[gr * 32 + j] = s;
  }
}

// ---------------- head (fp32) ----------------
__global__ __launch_bounds__(256) void head_kernel(
    const float* __restrict__ g, const float* __restrict__ W1, const float* __restrict__ b1,
    const float* __restrict__ W2, const float* __restrict__ b2, float* __restrict__ out) {
  __shared__ float sW1[1024], sb1[32];
  __shared__ float sW2[64], sb2[2];
  __shared__ float zb[8][33], tb[8][33], lb[8][2];
  int tid = threadIdx.x;
  for (int i = tid; i < 1024; i += 256) sW1[i] = W1[i];
  if (tid < 64) sW2[tid] = W2[tid];
  if (tid < 32) sb1[tid] = b1[tid];
  if (tid < 2) sb2[tid] = b2[tid];
  int nd = tid >> 5;
  int gr = blockIdx.x * 8 + nd;
  int j = tid & 31;
  __syncthreads();
  float z = (gr < N_GRAPHS) ? g[gr * 32 + j] : 0.f;
  zb[nd][j] = z;
  __syncthreads();
  float t = sb1[j];
#pragma unroll
  for (int k = 0; k < 32; ++k) t = fmaf(zb[nd][k], sW1[k * 32 + j], t);
  t = fmaxf(t, 0.f);
  tb[nd][j] = t;
  __syncthreads();
  if (j < 2) {
    float l = sb2[j];
#pragma unroll
    for (int k = 0; k < 32; ++k) l = fmaf(tb[nd][k], sW2[k * 2 + j], l);
    lb[nd][j] = l;
  }
  __syncthreads();
  if (gr < N_GRAPHS && j < 2) {
    float l0 = lb[nd][0], l1 = lb[nd][1];
    float m = fmaxf(l0, l1);
    float lse = m + logf(expf(l0 - m) + expf(l1 - m));
    out[gr * 2 + j] = lb[nd][j] - lse;
  }
}

extern "C" void kernel_launch(void* const* d_in, const int* in_sizes, int n_in,
                              void* d_out, int out_size, void* d_ws, size_t ws_size,
                              hipStream_t stream) {
  const float* x     = (const float*)d_in[0];
  const int*   eidx  = (const int*)d_in[1];
  const int*   batch = (const int*)d_in[2];
  const float* c1W1  = (const float*)d_in[3];
  const float* c1b1  = (const float*)d_in[4];
  const float* c1W2  = (const float*)d_in[5];
  const float* c1b2  = (const float*)d_in[6];
  const float* csW1  = (const float*)d_in[7];
  const float* csb1  = (const float*)d_in[8];
  const float* csW2  = (const float*)d_in[9];
  const float* csb2  = (const float*)d_in[10];
  const float* bng   = (const float*)d_in[11];
  const float* bnb   = (const float*)d_in[12];
  const float* bnm   = (const float*)d_in[13];
  const float* bnv   = (const float*)d_in[14];
  const float* fc1W  = (const float*)d_in[15];
  const float* fc1b  = (const float*)d_in[16];
  const float* fc2W  = (const float*)d_in[17];
  const float* fc2b  = (const float*)d_in[18];
  float* out = (float*)d_out;

  const int* src = eidx;
  const int* dst = eidx + N_EDGES;

  // workspace (~50.6 MB)
  char* p = (char*)d_ws;
  unsigned short* hA16 = (unsigned short*)p; p += (size_t)N_NODES * 32 * 2;   // 6.4 MB
  unsigned short* hB16 = (unsigned short*)p; p += (size_t)N_NODES * 32 * 2;   // 6.4 MB
  int*      cnt  = (int*)p;      p += (size_t)N_NODES * 4;                    // 0.4 MB
  int*      csr  = (int*)p;      p += (size_t)NBKT * 128 * MAXDEG * 4;        // 25.6 MB
  unsigned* ebuf = (unsigned*)p; p += (size_t)NBKT * BCAP * 4;                // 11.2 MB
  int*      gCur = (int*)p;      p += 1024 * 4;
  float*    g    = (float*)p;    p += (size_t)N_GRAPHS * 32 * 4;

  // ---- build: bucket pass + per-bucket padded-CSR pass ----
  hipMemsetAsync(gCur, 0, 1024 * 4, stream);
  b1_bucket<<<(N_EDGES + E_PER_BLK - 1) / E_PER_BLK, 1024, 0, stream>>>(src, dst, gCur, ebuf);
  b2_csr<<<NBKT, 256, 0, stream>>>(ebuf, gCur, cnt, csr);

  // ---- conv1 (7->32) + relu + bn0, bf16 out ----
  gin_layer7<<<N_NODES / 4, 256, 0, stream>>>(
      x, cnt, csr, c1W1, c1b1, c1W2, c1b2, bng, bnb, bnm, bnv, hA16);

  // ---- conv2..5 (32->32) + relu + bn1..4, persistent-wave lean layer ----
  unsigned short* cur = hA16;
  unsigned short* nxt = hB16;
  for (int i = 0; i < 4; ++i) {
    gin_layer32<<<2048, 256, 0, stream>>>(
        cur, cnt, csr,
        csW1 + (size_t)i * 1024, csb1 + (size_t)i * 32,
        csW2 + (size_t)i * 1024, csb2 + (size_t)i * 32,
        bng + (size_t)(i + 1) * 32, bnb + (size_t)(i + 1) * 32,
        bnm + (size_t)(i + 1) * 32, bnv + (size_t)(i + 1) * 32, nxt);
    unsigned short* tmp = cur; cur = nxt; nxt = tmp;
  }

  pool_kernel<<<N_GRAPHS, 256, 0, stream>>>(cur, batch, g);
  head_kernel<<<(N_GRAPHS + 7) / 8, 256, 0, stream>>>(g, fc1W, fc1b, fc2W, fc2b, out);
}